// Round 1
// 213.475 us; speedup vs baseline: 1.0163x; 1.0163x over previous
//
#include <hip/hip_runtime.h>
#include <stdint.h>

#define NB 32768
#define NPASS 4
#define FULL27 0x07FFFFFFu
#define NBF (NB * 729)     // total floats = 23,887,872
#define PPW 16             // puzzles per wave-block: 4 lanes/puzzle (quad-aligned, band 3 idle)
#define NBLK (NB / PPW)    // 2048 blocks exactly (8 blocks/CU), no tail
#define ROUNDS 183         // ceil(16*729 / 64) ballot rounds
#define POOLDW 368         // 2*ROUNDS = 366 dwords (+pad)

// Per-band bitboard: digit d, band b (rows 3b..3b+2), bit (r*9+c).
// BOX k mask within band: 0x1C0E07 << 3k ; COL c: 0x40201 << c ; ROW r: 0x1FF << 9r
// Flat float layout: puzzle p, digit d, band b, cell j  ==  p*729 + d*81 + b*27 + j.
//
// SESSION LEDGER:
//   r15 (prev session best, 216.5us): 3 lanes/puzzle, PPW=20, 1639 waves,
//     cross-band via ds_bpermute __shfl. pack ~37us solve ~50us expand ~12us
//     + ~110us harness-fixed. Counters: Occ 14%, VALUBusy 42%, LDS_CONF 3.0M.
//   r16 (this round): quad-aligned bands — 4 lanes/puzzle, PPW=16, 2048 waves,
//     all 36x4 cross-band shuffles replaced by DPP quad_perm (VALU, zero
//     latency, no DS). Predict: conflicts ~0, VALUBusy up, dur 107->~88us.

__device__ __forceinline__ uint32_t colfold(uint32_t w) {
    return (w | (w >> 9) | (w >> 18)) & 0x1FFu;
}
__device__ __forceinline__ uint32_t colmaj2(uint32_t w) {   // columns with >=2 bits in band
    return ((w & (w >> 9)) | ((w | (w >> 9)) & (w >> 18))) & 0x1FFu;
}
// quad_perm rotations within the 4-lane quad: lane b reads band (b+1)%3 / (b-1)%3.
// ctrl = sel0 | sel1<<2 | sel2<<4 | sel3<<6 : [1,2,0,0]=0x09 ; [2,0,1,0]=0x12
__device__ __forceinline__ uint32_t rotA(uint32_t v) {      // from band+1 (mod 3)
    return (uint32_t)__builtin_amdgcn_update_dpp(0, (int)v, 0x09, 0xF, 0xF, true);
}
__device__ __forceinline__ uint32_t rotB(uint32_t v) {      // from band-1 (mod 3)
    return (uint32_t)__builtin_amdgcn_update_dpp(0, (int)v, 0x12, 0xF, 0xF, true);
}

__global__ __launch_bounds__(64)
void sudoku_kernel(const uint32_t* __restrict__ in, float* __restrict__ out,
                   float* __restrict__ solved) {
    __shared__ uint32_t pool[POOLDW];       // 16*729 = 11664 bits = 365 dw (+pad)
    const int lane = threadIdx.x;
    const int trip = lane >> 2;             // puzzle slot 0..15
    const int band = lane & 3;              // 0..2 live, 3 idle in solve
    const int p0 = blockIdx.x * PPW;        // first puzzle of block
    const int p = p0 + trip;                // always < NB (grid exact)

    // ---------------- PACK: coalesced loads -> ballot -> wave-private pool ----------
    // Pool bit j == input float p0*729 + j (j in [0, 11664)). 183 rounds of 64.
    {
        const int base = p0 * 729;                      // < 24M, fits int
        #pragma unroll 1
        for (int c = 0; c < 11; ++c) {                  // 11 chunks x 16 rounds = 176
            uint32_t v[16];
            #pragma unroll
            for (int j = 0; j < 16; ++j) {
                int gi = base + (c * 16 + j) * 64 + lane;
                if (gi >= NBF) gi = NBF - 1;            // tail clamp (bits unused)
                v[j] = in[gi];
            }
            #pragma unroll
            for (int j = 0; j < 16; ++j) {
                unsigned long long m = __ballot(v[j] != 0u);
                if (lane == 0) {
                    int r = c * 16 + j;
                    pool[2 * r]     = (uint32_t)m;
                    pool[2 * r + 1] = (uint32_t)(m >> 32);
                }
            }
        }
        {   // rounds 176..182
            uint32_t v[7];
            #pragma unroll
            for (int j = 0; j < 7; ++j) {
                int gi = base + (176 + j) * 64 + lane;
                if (gi >= NBF) gi = NBF - 1;
                v[j] = in[gi];
            }
            #pragma unroll
            for (int j = 0; j < 7; ++j) {
                unsigned long long m = __ballot(v[j] != 0u);
                if (lane == 0) {
                    int r = 176 + j;
                    pool[2 * r]     = (uint32_t)m;
                    pool[2 * r + 1] = (uint32_t)(m >> 32);
                }
            }
        }
    }
    __syncthreads();

    // ---------------- EXTRACT: 9 band-words for this lane's puzzle ----------------
    uint32_t bd[9];
    {
        const int bb0 = trip * 729 + band * 27;         // band=3 reads garbage in-bounds
        #pragma unroll
        for (int d = 0; d < 9; ++d) {
            int bb = bb0 + d * 81;
            int di = bb >> 5, sh = bb & 31;
            uint64_t both = (uint64_t)pool[di] | ((uint64_t)pool[di + 1] << 32);
            bd[d] = (uint32_t)(both >> sh) & FULL27;
        }
    }
    __syncthreads();    // extraction done before the pool is zeroed for expand

    // ---------------- SOLVE (validated r6/r8 logic; shuffles -> DPP) ----------------
    #pragma unroll 1
    for (int pass = 0; pass < NPASS; ++pass) {
        // ---------- filter 'box' (band-local) ----------
        {
            uint32_t on = 0, tw = 0, fo = 0;
            #pragma unroll
            for (int d = 0; d < 9; ++d) {
                uint32_t c = on & bd[d];
                on ^= bd[d]; fo |= tw & c; tw ^= c;
            }
            uint32_t ex1 = on & ~tw & ~fo;
            #pragma unroll
            for (int d = 0; d < 9; ++d) {
                uint32_t s = bd[d] & ex1;
                #pragma unroll
                for (int k = 0; k < 3; ++k) {
                    uint32_t bm = 0x1C0E07u << (3 * k);
                    uint32_t sm = s & bm;
                    uint32_t multi = sm & (sm - 1u);
                    uint32_t keep = (sm == 0u) ? 0xFFFFFFFFu : (~bm | (multi ? 0u : sm));
                    bd[d] &= keep;
                }
            }
        }

        // ---------- pointing 'h' (band-local) ----------
        #pragma unroll
        for (int d = 0; d < 9; ++d) {
            uint32_t w = bd[d];
            uint32_t t = (w | (w >> 1) | (w >> 2)) & 0x01249249u;
            uint32_t sum = (t & 0x1FFu) + ((t >> 9) & 0x1FFu) + ((t >> 18) & 0x1FFu);
            uint32_t single = sum & ~(sum >> 1) & 0x49u;
            uint32_t point = t & (single * 0x40201u);
            uint32_t clearm = 0;
            #pragma unroll
            for (int r = 0; r < 3; ++r) {
                uint32_t pr = (point >> (9 * r)) & 0x1FFu;
                uint32_t multi = pr & (pr - 1u);
                uint32_t segkeep = multi ? 0u : pr * 7u;
                uint32_t rc = pr ? ((0x1FFu & ~segkeep) << (9 * r)) : 0u;
                clearm |= rc;
            }
            bd[d] = w & ~clearm;
        }

        // ---------- pointing 'v' (cross-band via DPP) ----------
        {
            uint32_t pnt[9];
            #pragma unroll
            for (int d = 0; d < 9; ++d) {
                uint32_t w = bd[d];
                uint32_t q = colfold(w);
                uint32_t u = (q & 0x49u) + ((q >> 1) & 0x49u) + ((q >> 2) & 0x49u);
                uint32_t single = u & ~(u >> 1) & 0x49u;
                pnt[d] = q & (single * 7u);
            }
            #pragma unroll
            for (int d = 0; d < 9; ++d) {
                uint32_t o = rotA(pnt[d]) | rotB(pnt[d]);
                bd[d] &= ~(o * 0x40201u);
            }
        }

        // ---------- unique 'h' (band-local) ----------
        {
            uint32_t hid[9], has = 0;
            #pragma unroll
            for (int d = 0; d < 9; ++d) {
                uint32_t w = bd[d], h = 0;
                #pragma unroll
                for (int r = 0; r < 3; ++r) {
                    uint32_t x = w & (0x1FFu << (9 * r));
                    h |= (x & (x - 1u)) ? 0u : x;
                }
                hid[d] = h; has |= h;
            }
            #pragma unroll
            for (int d = 0; d < 9; ++d) bd[d] = (bd[d] & ~has) | hid[d];
        }

        // ---------- unique 'v' (cross-band via DPP) ----------
        {
            uint32_t hid[9], has = 0;
            #pragma unroll
            for (int d = 0; d < 9; ++d) {
                uint32_t w = bd[d];
                uint32_t q0 = colfold(w), m0 = colmaj2(w);
                uint32_t ex = q0 | (m0 << 9);
                uint32_t ea = rotA(ex);
                uint32_t eb = rotB(ex);
                uint32_t qa = ea & 0x1FFu, ma = ea >> 9;
                uint32_t qb = eb & 0x1FFu, mb = eb >> 9;
                uint32_t ge2 = m0 | ma | mb | (q0 & qa) | (q0 & qb) | (qa & qb);
                uint32_t ex1c = (q0 | qa | qb) & ~ge2;   // column total count == 1
                hid[d] = w & ((ex1c & q0) * 0x40201u);
                has |= hid[d];
            }
            #pragma unroll
            for (int d = 0; d < 9; ++d) bd[d] = (bd[d] & ~has) | hid[d];
        }

        // ---------- unique 'box' (band-local) ----------
        {
            uint32_t hid[9], has = 0;
            #pragma unroll
            for (int d = 0; d < 9; ++d) {
                uint32_t w = bd[d], h = 0;
                #pragma unroll
                for (int k = 0; k < 3; ++k) {
                    uint32_t x = w & (0x1C0E07u << (3 * k));
                    h |= (x & (x - 1u)) ? 0u : x;
                }
                hid[d] = h; has |= h;
            }
            #pragma unroll
            for (int d = 0; d < 9; ++d) bd[d] = (bd[d] & ~has) | hid[d];
        }

        // ---------- doubles 'v' twice (cross-band via DPP) ----------
        #pragma unroll 1
        for (int rep = 0; rep < 2; ++rep) {
            uint32_t on = 0, tw = 0, fo = 0;
            #pragma unroll
            for (int d = 0; d < 9; ++d) {
                uint32_t c = on & bd[d];
                on ^= bd[d]; fo |= tw & c; tw ^= c;
            }
            uint32_t ex2 = tw & ~on & ~fo;
            uint32_t Q[9], K[9];
            #pragma unroll
            for (int d = 0; d < 9; ++d) { Q[d] = bd[d] & ex2; K[d] = 0u; }
            #pragma unroll
            for (int d1 = 0; d1 < 9; ++d1)
                #pragma unroll
                for (int d2 = d1 + 1; d2 < 9; ++d2) {
                    uint32_t P = Q[d1] & Q[d2];
                    uint32_t f0 = colfold(P), g0 = colmaj2(P);
                    uint32_t ex = f0 | (g0 << 9);
                    uint32_t ea = rotA(ex);
                    uint32_t eb = rotB(ex);
                    uint32_t fa = ea & 0x1FFu, ga = ea >> 9;
                    uint32_t fb = eb & 0x1FFu, gb = eb >> 9;
                    // columns with >=2 exact-pair cells across the full column
                    uint32_t dup = g0 | ga | gb | (f0 & fa) | (f0 & fb) | (fa & fb);
                    uint32_t sK = P & (dup * 0x40201u);
                    K[d1] |= sK; K[d2] |= sK;
                }
            #pragma unroll
            for (int d = 0; d < 9; ++d) {
                uint32_t kc = colfold(K[d]);
                uint32_t cols = kc | rotA(kc) | rotB(kc);
                uint32_t em = cols * 0x40201u;
                bd[d] = (bd[d] & ~em) | K[d];
            }
        }

        // ---------- doubles 'box' (band-local) ----------
        {
            uint32_t on = 0, tw = 0, fo = 0;
            #pragma unroll
            for (int d = 0; d < 9; ++d) {
                uint32_t c = on & bd[d];
                on ^= bd[d]; fo |= tw & c; tw ^= c;
            }
            uint32_t ex2 = tw & ~on & ~fo;
            uint32_t Q[9], K[9];
            #pragma unroll
            for (int d = 0; d < 9; ++d) { Q[d] = bd[d] & ex2; K[d] = 0u; }
            #pragma unroll
            for (int d1 = 0; d1 < 9; ++d1)
                #pragma unroll
                for (int d2 = d1 + 1; d2 < 9; ++d2) {
                    uint32_t P = Q[d1] & Q[d2];
                    #pragma unroll
                    for (int k = 0; k < 3; ++k) {
                        uint32_t m = P & (0x1C0E07u << (3 * k));
                        uint32_t s = (m & (m - 1u)) ? m : 0u;
                        K[d1] |= s; K[d2] |= s;
                    }
                }
            #pragma unroll
            for (int d = 0; d < 9; ++d)
                #pragma unroll
                for (int k = 0; k < 3; ++k) {
                    uint32_t bm = 0x1C0E07u << (3 * k);
                    uint32_t t = K[d] & bm;
                    uint32_t mask = t ? (~bm | t) : 0xFFFFFFFFu;
                    bd[d] &= mask;
                }
        }
    } // passes

    // ---------------- solved flag (AND across quad via DPP) ----------------
    {
        uint32_t on = 0, tw = 0, fo = 0;
        #pragma unroll
        for (int d = 0; d < 9; ++d) {
            uint32_t c = on & bd[d];
            on ^= bd[d]; fo |= tw & c; tw ^= c;
        }
        uint32_t okb = ((on & ~tw & ~fo) == FULL27) ? 1u : 0u;
        uint32_t all = okb & rotA(okb) & rotB(okb);
        if (band == 0) solved[p] = all ? 1.0f : 0.0f;
    }

    // ---------------- EXPAND: pool -> float4 stores ----------------
    // Bit B of pool == float p0*729 + B. Zero -> barrier -> atomicOr -> barrier.
    for (int j = lane; j < POOLDW; j += 64) pool[j] = 0u;
    __syncthreads();
    if (band != 3) {
        const int pbit = trip * 729;
        #pragma unroll
        for (int d = 0; d < 9; ++d) {
            int bitbase = pbit + d * 81 + band * 27;
            int di = bitbase >> 5;
            int sh = bitbase & 31;
            uint64_t both = (uint64_t)bd[d] << sh;
            atomicOr(&pool[di], (uint32_t)both);
            atomicOr(&pool[di + 1], (uint32_t)(both >> 32));
        }
    }
    __syncthreads();
    {
        const int limit4 = PPW * 729 / 4;                    // 2916 (exact, no tail block)
        float4* dst4 = (float4*)(out + (size_t)p0 * 729);    // p0*729 ≡ 0 mod 4: aligned
        #pragma unroll 4
        for (int i = 0; i < 46; ++i) {                       // 46*64 = 2944 >= 2916
            int j = i * 64 + lane;
            if (j < limit4) {
                uint32_t nib = (pool[j >> 3] >> ((j & 7) * 4)) & 0xFu;
                dst4[j] = make_float4((float)(nib & 1u), (float)((nib >> 1) & 1u),
                                      (float)((nib >> 2) & 1u), (float)((nib >> 3) & 1u));
            }
        }
    }
}

extern "C" void kernel_launch(void* const* d_in, const int* in_sizes, int n_in,
                              void* d_out, int out_size, void* d_ws, size_t ws_size,
                              hipStream_t stream) {
    const uint32_t* in = (const uint32_t*)d_in[0];   // float32 bits; nonzero <=> 1.0f
    float* out = (float*)d_out;
    float* solved = out + (size_t)NB * 729;
    // 2048 one-wave blocks (16 puzzles each) -> 8 blocks/CU exact
    sudoku_kernel<<<NBLK, 64, 0, stream>>>(in, out, solved);
}